// Round 7
// baseline (67.334 us; speedup 1.0000x reference)
//
#include <hip/hip_runtime.h>
#include <math.h>

// ---------------------------------------------------------------------------
// Batched PDHG (Chambolle-Pock), one wave per sample, lane t owns time step t.
// Round-7 structure (delta vs round 6):
//  - GRID: 128 blocks x 512 threads (8 samples per block) -> 2 waves per SIMD
//    (block waves stay on one CU), filling the ~40% single-wave issue stall.
//  - shifts back to __shfl (ds_bpermute): 1 instr each, latency hidden under
//    the G-row block (R4 vs R5 measured bpermute > DPP+fixups).
//  - per-lane-zeroed constants (Avec, tsA/Bi/Bo, npts, C12) replace the two
//    `lt ?` cndmasks in the kts / u paths.
//  - keeps R6's u-package: both cross-lane shifts co-issued, one shift on the
//    serial cycle.
// ---------------------------------------------------------------------------

#define TT 48
#define N_ITERS 300
#define WPB 8          // waves (= samples) per block

typedef float v2 __attribute__((ext_vector_type(2)));

__device__ __forceinline__ v2 vfma(v2 a, v2 b, v2 c) {
    return __builtin_elementwise_fma(a, b, c);
}
__device__ __forceinline__ v2 vmax0(v2 a) {
    return __builtin_elementwise_max(a, (v2)(0.f));
}

__global__ __launch_bounds__(WPB * 64) void pdhg_kernel(
    const float* __restrict__ price,
    const float* __restrict__ loadv,
    const float* __restrict__ pvv,
    const float* __restrict__ s0,
    float* __restrict__ out,
    int B,
    float tau)
{
    const int wave = threadIdx.x >> 6;
    const int t    = threadIdx.x & 63;
    const int b    = blockIdx.x * WPB + wave;
    if (b >= B) return;

    const bool lt  = (t < TT);
    const bool i48 = (t == TT);

    const float A  = 0.999f;
    const float Bi = 0.95f;    // B00
    const float Bo = -1.05f;   // B01
    const float ts = tau * tau;     // tau*sigma (sigma == tau)

    float pr_ = 0.f, ld = 0.f, pv_ = 0.f;
    if (lt) {
        pr_ = price[(size_t)b*TT + t];
        ld  = loadv[(size_t)b*TT + t];
        pv_ = pvv  [(size_t)b*TT + t];
    }
    const float qe   = i48 ? s0[b] : 0.f;   // b_eq: zeros(T) then s0
    const float tsqe = ts * qe;

    // hoisted per-lane constants (zeroed on lanes >= 48 where needed so the
    // kts / u paths need no cndmask)
    const v2 tsv   = (v2)(ts);
    const v2 ntsv  = (v2)(-ts);
    const v2 npts  = lt ? (v2){ -ts, ts } : (v2){ 0.f, 0.f };
    const v2 BiBov = { -Bi, -Bo };
    const float Avec  = lt ? A       : 0.f;
    const float tsAl  = lt ? ts * A  : 0.f;
    const float tsBil = lt ? ts * Bi : 0.f;
    const float tsBol = lt ? ts * Bo : 0.f;
    const v2 tpv   = { tau * pr_, -tau * pr_ };    // tau*c for (in,out)/(pl,pr)
    const float tep = tau * 1.0e4f;                // tau*c_eps
    const v2 C12   = lt ? (v2){ 0.f, ts * 13.5f } : (v2){ 0.f, 0.f };
    const v2 C35   = { ts * 5.f,   ts * 5.f   };
    const v2 C79   = { ts * (-ld), ts * (-pv_) };
    const v2 C810  = { ts * ld,    ts * pv_   };
    const v2 C1112 = { ts * 10.f,  ts * 10.f  };

    // lane indices for the two cross-lane shifts (loop-invariant)
    const int prevLane = (t == 0)  ? TT : (t - 1);  // u[l-1], wrap lane0 <- 48
    const int nextLane = (t >= TT) ? 0  : (t + 1);  // zs[l+1], lane48 <- 0

    // primal state: pairs (in,out), (pl,pr), (s,eps)
    v2 xIO = (v2)(0.f), xPP = (v2)(0.f), xSE = (v2)(0.f);
    // dual state (scaled by tau): ye scalar (+ yprev = shifted ye); rows paired
    float ye = 0.f, yprev = 0.f;
    v2 G12 = (v2)(0.f), G35 = (v2)(0.f), G46 = (v2)(0.f),
       G79 = (v2)(0.f), G810 = (v2)(0.f), G1112 = (v2)(0.f);

    #pragma unroll 2
    for (int it = 0; it < N_ITERS; ++it) {
        // ---- K^T y on scaled duals (= tau * K^T y) ----
        const v2 dv    = G1112 - G1112.yx;          // {d1112, -d1112}
        const v2 ktIO  = vfma((v2)(ye), BiBov, (G35 - G46) + dv);
        const v2 ktPP  = (G810 - G79) + dv;
        const v2 S     = G79 + G810;
        const float wep = tep - (S.x + S.y);        // tau*(c_ep + ktep)
        // lanes >= 48: G12 pinned to 0 (npts/C12 zeroed), Avec = 0 -> kts = yprev
        const float kts = fmaf(-Avec, ye, yprev + (G12.y - G12.x));

        // ---- x' = x - w;  z = x' - w ----
        const v2 wIO = ktIO + tpv;
        const v2 wPP = ktPP + tpv;
        const v2 wSE = { kts, wep };
        const v2 xnIO = xIO - wIO;  const v2 zIO = xnIO - wIO;
        const v2 xnPP = xPP - wPP;  const v2 zPP = xnPP - wPP;
        const v2 xnSE = xSE - wSE;  const v2 zSE = xnSE - wSE;
        const float zs = zSE.x;

        // ---- u package: ye - ts*qe + ts*(own-lane part of K z eq-row) ----
        // (tsAl/tsBil/tsBol zeroed on lanes >= 48 -> u = ye - tsqe there)
        float u = ye - tsqe;
        u = fmaf(-tsBol, zIO.y, u);
        u = fmaf(-tsBil, zIO.x, u);
        u = fmaf(-tsAl,  zs,    u);

        // ---- both shifts co-issued (no dependency between them) ----
        const float zsn = __shfl(zs, nextLane);     // lane48 <- zs[0]
        const float us  = __shfl(u,  prevLane);     // lane0  <- u[48]

        // ---- dual rows: G' = max(G + ts*e - ts*h, 0) ----
        const v2 m11v = (zIO - zIO.yx) + (zPP - zPP.yx);  // {m11, -m11}
        G12   = vmax0(vfma(zSE.xx, npts, G12)  - C12);
        G35   = vmax0(vfma(zIO,    tsv,  G35)  - C35);
        G46   = vmax0(vfma(zIO,    ntsv, G46));
        G79   = vmax0(vfma(zSE.yy, ntsv, vfma(zPP, ntsv, G79))  - C79);
        G810  = vmax0(vfma(zSE.yy, ntsv, vfma(zPP, tsv,  G810)) - C810);
        G1112 = vmax0(vfma(m11v,   tsv,  G1112) - C1112);

        // ---- equality dual + pre-shifted ye for next iteration ----
        ye    = fmaf(ts, zsn, u);                   // ye_{i+1}[l]
        yprev = fmaf(ts, zs,  us);                  // ye_{i+1}[l-1] (wrap at 0)

        xSE = xnSE; xIO = xnIO; xPP = xnPP;
    }

    if (lt) {
        const size_t BT   = (size_t)B * TT;
        const size_t base = (size_t)b * TT + t;
        out[0*BT + base] = xIO.x;  // Ps_in
        out[1*BT + base] = xIO.y;  // Ps_out
        out[2*BT + base] = xPP.x;  // Pl
        out[3*BT + base] = xPP.y;  // Pr
        out[4*BT + base] = xSE.y;  // eps
    }
}

// ---------------------------------------------------------------------------
// Host: ||K||_2 via matrix-free Lanczos (m=56, no reorth) on M = K^T K
// (289-dim closed form), lambda_max(T_m) via Sturm bisection. Deterministic.
// ---------------------------------------------------------------------------
static float compute_tau_host()
{
    const double A = 0.999, Bi = 0.95, Bo = -1.05;
    const int n = 289;            // 49 + 5*48
    const int OS = 0, OI = 49, OO = 97, OPL = 145, OPR = 193, OE = 241;

    double q[289], qp[289], w[289];

    auto applyM = [&](const double* v, double* u) {
        double we[TT + 1];
        for (int t = 0; t < TT; ++t)
            we[t] = v[OS + t + 1] - A * v[OS + t] - Bi * v[OI + t] - Bo * v[OO + t];
        we[TT] = v[OS + 0];
        for (int j = 0; j <= TT; ++j) {
            double r = (j >= 1) ? we[j - 1] : we[TT];
            if (j <= TT - 1) r += -A * we[j] + 2.0 * v[OS + j];
            u[OS + j] = r;
        }
        for (int t = 0; t < TT; ++t) {
            const double w11 = v[OI + t] - v[OO + t] + v[OPL + t] - v[OPR + t];
            u[OI  + t] = -Bi * we[t] + 2.0 * v[OI  + t] + 2.0 * w11;
            u[OO  + t] = -Bo * we[t] + 2.0 * v[OO  + t] - 2.0 * w11;
            u[OPL + t] =  2.0 * v[OPL + t] + 2.0 * w11;
            u[OPR + t] =  2.0 * v[OPR + t] - 2.0 * w11;
            u[OE  + t] =  4.0 * v[OE  + t];
        }
    };

    // deterministic init, normalized
    unsigned long long lcg = 0x243F6A8885A308D3ull;
    for (int i = 0; i < n; ++i) {
        lcg = lcg * 6364136223846793005ull + 1442695040888963407ull;
        q[i] = ((double)(lcg >> 11) / 9007199254740992.0) - 0.5;
    }
    {
        double s = 0; for (int i = 0; i < n; ++i) s += q[i]*q[i];
        const double inv = 1.0 / sqrt(s);
        for (int i = 0; i < n; ++i) q[i] *= inv;
    }

    const int MMAX = 56;
    double alpha[MMAX], beta[MMAX];
    for (int i = 0; i < n; ++i) qp[i] = 0.0;
    double bprev = 0.0;
    int m = MMAX;
    for (int j = 0; j < MMAX; ++j) {
        applyM(q, w);
        if (j > 0) for (int i = 0; i < n; ++i) w[i] -= bprev * qp[i];
        double a = 0; for (int i = 0; i < n; ++i) a += w[i] * q[i];
        alpha[j] = a;
        for (int i = 0; i < n; ++i) w[i] -= a * q[i];
        double s = 0; for (int i = 0; i < n; ++i) s += w[i]*w[i];
        const double bnx = sqrt(s);
        if (bnx < 1e-12) { m = j + 1; break; }
        beta[j] = bnx;
        const double inv = 1.0 / bnx;
        for (int i = 0; i < n; ++i) { qp[i] = q[i]; q[i] = w[i] * inv; }
        bprev = bnx;
    }

    double hi = 0.0;
    for (int i = 0; i < m; ++i) {
        double g = alpha[i] + (i > 0 ? fabs(beta[i-1]) : 0.0)
                            + (i < m-1 ? fabs(beta[i]) : 0.0);
        if (g > hi) hi = g;
    }
    hi += 1e-9; double lo = 0.0;
    for (int it = 0; it < 64; ++it) {
        const double mid = 0.5 * (lo + hi);
        int cnt = 0; double d = 1.0;
        for (int i = 0; i < m; ++i) {
            double tt = alpha[i] - mid - (i > 0 ? beta[i-1]*beta[i-1] / d : 0.0);
            if (tt < 0) ++cnt;
            if (fabs(tt) < 1e-30) tt = -1e-30;
            d = tt;
        }
        if (cnt >= m) hi = mid; else lo = mid;
    }
    double lam = 0.5 * (lo + hi);

    applyM(q, w);
    double rq = 0, nq = 0;
    for (int i = 0; i < n; ++i) { rq += q[i]*w[i]; nq += q[i]*q[i]; }
    rq /= nq;
    if (rq > lam) lam = rq;

    return (float)(0.95 / sqrt(lam));
}

extern "C" void kernel_launch(void* const* d_in, const int* in_sizes, int n_in,
                              void* d_out, int out_size, void* d_ws, size_t ws_size,
                              hipStream_t stream)
{
    const float* price = (const float*)d_in[0];
    const float* loadv = (const float*)d_in[1];
    const float* pvv   = (const float*)d_in[2];
    const float* s0    = (const float*)d_in[3];
    float* out = (float*)d_out;

    const int B = in_sizes[0] / TT;   // price_hat is (B, T)
    const float tau = compute_tau_host();

    const int grid = (B + WPB - 1) / WPB;
    pdhg_kernel<<<grid, WPB * 64, 0, stream>>>(price, loadv, pvv, s0, out, B, tau);
}

// Round 9
// 40.272 us; speedup vs baseline: 1.6720x; 1.6720x over previous
//
#include <hip/hip_runtime.h>
#include <math.h>

// ---------------------------------------------------------------------------
// Batched PDHG (Chambolle-Pock), one wave per sample, lane t owns time step t.
// Round-9 structure = best measured config (R6, harness 43.8us) + op cuts:
//  - wave-DPP shifts (wave_shr:1 / wave_shl:1 + readlane/cndmask wrap fixup)
//  - u-package: one cross-lane shift on the serial cycle, both shifts co-issued
//  - zeroed per-lane constants kill the kts / u cndmasks (lanes >= 48:
//    Avec=tsA=tsBi=tsBo=0, npts=C12=0 pins G12=0 -> kts=yprev, u=ye-tsqe)
//  - folds: z = fma(-2,w,x); zPP2 = zPP - {ld,pv} absorbs C79/C810 and shifts
//    C1112; m11v from one packed swizzle-sub
//  - N_ITERS = 300 (mandatory: truncation to 208 measured absmax 1.875 -
//    LP-PDHG tail contracts too slowly, iteration count is not negotiable)
// ---------------------------------------------------------------------------

#define TT 48
#define N_ITERS 300

typedef float v2 __attribute__((ext_vector_type(2)));

__device__ __forceinline__ v2 vfma(v2 a, v2 b, v2 c) {
    return __builtin_elementwise_fma(a, b, c);
}
__device__ __forceinline__ v2 vmax0(v2 a) {
    return __builtin_elementwise_max(a, (v2)(0.f));
}

// lane l <- v[l-1] (whole wave), lane 0 <- v[48]
__device__ __forceinline__ float shift_up(float v, bool is0) {
    int iv  = __float_as_int(v);
    int s48 = __builtin_amdgcn_readlane(iv, 48);
    int sh  = __builtin_amdgcn_update_dpp(iv, iv, 0x138, 0xF, 0xF, false); // wave_shr:1
    sh = is0 ? s48 : sh;
    return __int_as_float(sh);
}

// lane l <- v[l+1] (whole wave), lane 48 <- v[0]
__device__ __forceinline__ float shift_dn(float v, bool is48) {
    int iv = __float_as_int(v);
    int s0 = __builtin_amdgcn_readlane(iv, 0);
    int sh = __builtin_amdgcn_update_dpp(iv, iv, 0x130, 0xF, 0xF, false); // wave_shl:1
    sh = is48 ? s0 : sh;
    return __int_as_float(sh);
}

__global__ __launch_bounds__(64) void pdhg_kernel(
    const float* __restrict__ price,
    const float* __restrict__ loadv,
    const float* __restrict__ pvv,
    const float* __restrict__ s0,
    float* __restrict__ out,
    int B,
    float tau)
{
    const int b = blockIdx.x;
    const int t = threadIdx.x;
    const bool lt  = (t < TT);
    const bool i48 = (t == TT);
    const bool i0  = (t == 0);

    const float A  = 0.999f;
    const float Bi = 0.95f;    // B00
    const float Bo = -1.05f;   // B01
    const float ts = tau * tau;     // tau*sigma (sigma == tau)

    float pr_ = 0.f, ld = 0.f, pv_ = 0.f;
    if (lt) {
        pr_ = price[(size_t)b*TT + t];
        ld  = loadv[(size_t)b*TT + t];
        pv_ = pvv  [(size_t)b*TT + t];
    }
    const float qe   = i48 ? s0[b] : 0.f;   // b_eq: zeros(T) then s0
    const float tsqe = ts * qe;

    // hoisted per-lane constants (zeroed on lanes >= 48 where needed so the
    // kts / u paths need no cndmask; G12 stays pinned at 0 there)
    const v2 tsv   = (v2)(ts);
    const v2 ntsv  = (v2)(-ts);
    const v2 npts  = lt ? (v2){ -ts, ts } : (v2){ 0.f, 0.f };
    const v2 BiBov = { -Bi, -Bo };
    const float Avec  = lt ? A       : 0.f;
    const float tsAl  = lt ? ts * A  : 0.f;
    const float tsBil = lt ? ts * Bi : 0.f;
    const float tsBol = lt ? ts * Bo : 0.f;
    const v2 tpv   = { tau * pr_, -tau * pr_ };    // tau*c for (in,out)/(pl,pr)
    const float tep = tau * 1.0e4f;                // tau*c_eps
    const v2 LDPV  = { ld, pv_ };                  // zPP' shift
    const float dlp = ld - pv_;                    // m11 constant offset
    const v2 C12    = lt ? (v2){ 0.f, ts * 13.5f } : (v2){ 0.f, 0.f };
    const v2 C35    = { ts * 5.f, ts * 5.f };
    const v2 C1112d = { ts * (10.f - dlp), ts * (10.f + dlp) };

    // primal state: pairs (in,out), (pl,pr), (s,eps)
    v2 xIO = (v2)(0.f), xPP = (v2)(0.f), xSE = (v2)(0.f);
    // dual state (scaled by tau): ye scalar (+ yprev = shifted ye); rows paired
    float ye = 0.f, yprev = 0.f;
    v2 G12 = (v2)(0.f), G35 = (v2)(0.f), G46 = (v2)(0.f),
       G79 = (v2)(0.f), G810 = (v2)(0.f), G1112 = (v2)(0.f);

    #pragma unroll 2
    for (int it = 0; it < N_ITERS; ++it) {
        // ---- K^T y on scaled duals (= tau * K^T y) ----
        const v2 dv    = G1112 - G1112.yx;          // {d1112, -d1112}
        const v2 ktIO  = vfma((v2)(ye), BiBov, (G35 - G46) + dv);
        const v2 ktPP  = (G810 - G79) + dv;
        const v2 S     = G79 + G810;
        const float wep = tep - (S.x + S.y);        // tau*(c_ep + ktep)
        // lanes >= 48: G12 pinned 0, Avec = 0 -> kts = yprev (no cndmask)
        const float kts = fmaf(-Avec, ye, yprev + (G12.y - G12.x));

        // ---- x' = x - w;  z = x - 2w ----
        const v2 wIO = ktIO + tpv;
        const v2 wPP = ktPP + tpv;
        const v2 wSE = { kts, wep };
        const v2 xnIO = xIO - wIO;  const v2 zIO = vfma(wIO, (v2)(-2.f), xIO);
        const v2 xnPP = xPP - wPP;  const v2 zPP = vfma(wPP, (v2)(-2.f), xPP);
        const v2 xnSE = xSE - wSE;  const v2 zSE = vfma(wSE, (v2)(-2.f), xSE);
        const float zs = zSE.x;

        // ---- u package: ye - ts*qe + ts*(own-lane part of K z eq-row) ----
        // (tsAl/tsBil/tsBol zeroed on lanes >= 48 -> u = ye - tsqe there)
        float u = ye - tsqe;
        u = fmaf(-tsBol, zIO.y, u);
        u = fmaf(-tsBil, zIO.x, u);
        u = fmaf(-tsAl,  zs,    u);

        // ---- both shifts co-issued (no dependency between them) ----
        const float zsn = shift_dn(zs, i48);        // lane48 <- zs[0]
        const float us  = shift_up(u,  i0);         // lane0  <- u[48]

        // ---- dual rows: G' = max(G + ts*e - ts*h, 0) ----
        const v2 zPP2 = zPP - LDPV;                 // (zpl-ld, zpr-pv)
        const v2 sv   = zPP2 + zSE.yy;
        const v2 dvv  = zPP2 - zSE.yy;
        const v2 S2   = zIO + zPP2;
        const v2 m11v = S2 - S2.yx;                 // {m11-dlp, -(m11-dlp)}

        G12   = vmax0(vfma(zSE.xx, npts, G12) - C12);
        G35   = vmax0(vfma(zIO,  tsv,  G35)  - C35);
        G46   = vmax0(vfma(zIO,  ntsv, G46));
        G79   = vmax0(vfma(sv,   ntsv, G79));           // C79 folded into zPP2
        G810  = vmax0(vfma(dvv,  tsv,  G810));          // C810 folded into zPP2
        G1112 = vmax0(vfma(m11v, tsv,  G1112) - C1112d);

        // ---- equality dual + pre-shifted ye for next iteration ----
        ye    = fmaf(ts, zsn, u);                   // ye_{i+1}[l]
        yprev = fmaf(ts, zs,  us);                  // ye_{i+1}[l-1] (wrap at 0)

        xSE = xnSE; xIO = xnIO; xPP = xnPP;
    }

    if (lt) {
        const size_t BT   = (size_t)B * TT;
        const size_t base = (size_t)b * TT + t;
        out[0*BT + base] = xIO.x;  // Ps_in
        out[1*BT + base] = xIO.y;  // Ps_out
        out[2*BT + base] = xPP.x;  // Pl
        out[3*BT + base] = xPP.y;  // Pr
        out[4*BT + base] = xSE.y;  // eps
    }
}

// ---------------------------------------------------------------------------
// Host: ||K||_2 via matrix-free Lanczos (m=56, no reorth) on M = K^T K
// (289-dim closed form), lambda_max(T_m) via Sturm bisection. Deterministic.
// ---------------------------------------------------------------------------
static float compute_tau_host()
{
    const double A = 0.999, Bi = 0.95, Bo = -1.05;
    const int n = 289;            // 49 + 5*48
    const int OS = 0, OI = 49, OO = 97, OPL = 145, OPR = 193, OE = 241;

    double q[289], qp[289], w[289];

    auto applyM = [&](const double* v, double* u) {
        double we[TT + 1];
        for (int t = 0; t < TT; ++t)
            we[t] = v[OS + t + 1] - A * v[OS + t] - Bi * v[OI + t] - Bo * v[OO + t];
        we[TT] = v[OS + 0];
        for (int j = 0; j <= TT; ++j) {
            double r = (j >= 1) ? we[j - 1] : we[TT];
            if (j <= TT - 1) r += -A * we[j] + 2.0 * v[OS + j];
            u[OS + j] = r;
        }
        for (int t = 0; t < TT; ++t) {
            const double w11 = v[OI + t] - v[OO + t] + v[OPL + t] - v[OPR + t];
            u[OI  + t] = -Bi * we[t] + 2.0 * v[OI  + t] + 2.0 * w11;
            u[OO  + t] = -Bo * we[t] + 2.0 * v[OO  + t] - 2.0 * w11;
            u[OPL + t] =  2.0 * v[OPL + t] + 2.0 * w11;
            u[OPR + t] =  2.0 * v[OPR + t] - 2.0 * w11;
            u[OE  + t] =  4.0 * v[OE  + t];
        }
    };

    // deterministic init, normalized
    unsigned long long lcg = 0x243F6A8885A308D3ull;
    for (int i = 0; i < n; ++i) {
        lcg = lcg * 6364136223846793005ull + 1442695040888963407ull;
        q[i] = ((double)(lcg >> 11) / 9007199254740992.0) - 0.5;
    }
    {
        double s = 0; for (int i = 0; i < n; ++i) s += q[i]*q[i];
        const double inv = 1.0 / sqrt(s);
        for (int i = 0; i < n; ++i) q[i] *= inv;
    }

    const int MMAX = 56;
    double alpha[MMAX], beta[MMAX];
    for (int i = 0; i < n; ++i) qp[i] = 0.0;
    double bprev = 0.0;
    int m = MMAX;
    for (int j = 0; j < MMAX; ++j) {
        applyM(q, w);
        if (j > 0) for (int i = 0; i < n; ++i) w[i] -= bprev * qp[i];
        double a = 0; for (int i = 0; i < n; ++i) a += w[i] * q[i];
        alpha[j] = a;
        for (int i = 0; i < n; ++i) w[i] -= a * q[i];
        double s = 0; for (int i = 0; i < n; ++i) s += w[i]*w[i];
        const double bnx = sqrt(s);
        if (bnx < 1e-12) { m = j + 1; break; }
        beta[j] = bnx;
        const double inv = 1.0 / bnx;
        for (int i = 0; i < n; ++i) { qp[i] = q[i]; q[i] = w[i] * inv; }
        bprev = bnx;
    }

    double hi = 0.0;
    for (int i = 0; i < m; ++i) {
        double g = alpha[i] + (i > 0 ? fabs(beta[i-1]) : 0.0)
                            + (i < m-1 ? fabs(beta[i]) : 0.0);
        if (g > hi) hi = g;
    }
    hi += 1e-9; double lo = 0.0;
    for (int it = 0; it < 64; ++it) {
        const double mid = 0.5 * (lo + hi);
        int cnt = 0; double d = 1.0;
        for (int i = 0; i < m; ++i) {
            double tt = alpha[i] - mid - (i > 0 ? beta[i-1]*beta[i-1] / d : 0.0);
            if (tt < 0) ++cnt;
            if (fabs(tt) < 1e-30) tt = -1e-30;
            d = tt;
        }
        if (cnt >= m) hi = mid; else lo = mid;
    }
    double lam = 0.5 * (lo + hi);

    applyM(q, w);
    double rq = 0, nq = 0;
    for (int i = 0; i < n; ++i) { rq += q[i]*w[i]; nq += q[i]*q[i]; }
    rq /= nq;
    if (rq > lam) lam = rq;

    return (float)(0.95 / sqrt(lam));
}

extern "C" void kernel_launch(void* const* d_in, const int* in_sizes, int n_in,
                              void* d_out, int out_size, void* d_ws, size_t ws_size,
                              hipStream_t stream)
{
    const float* price = (const float*)d_in[0];
    const float* loadv = (const float*)d_in[1];
    const float* pvv   = (const float*)d_in[2];
    const float* s0    = (const float*)d_in[3];
    float* out = (float*)d_out;

    const int B = in_sizes[0] / TT;   // price_hat is (B, T)
    const float tau = compute_tau_host();

    pdhg_kernel<<<B, 64, 0, stream>>>(price, loadv, pvv, s0, out, B, tau);
}

// Round 10
// 39.527 us; speedup vs baseline: 1.7035x; 1.0188x over previous
//
#include <hip/hip_runtime.h>
#include <math.h>

// ---------------------------------------------------------------------------
// Batched PDHG (Chambolle-Pock), one wave per sample, lane t owns time step t.
// Round-10 = round-9 (harness 40.3us) + loop-carried-chain shortening:
//  - K^T-side diffs (dG12, sumIO, dv, dPP, Ssum) computed in the TAIL right
//    after the G-updates (overlapping the independent ye/yprev ops) instead
//    of at the head of the next iteration -> shorter critical cycle, same ops.
//  - s-path hoisted to the top of the body; zs down-shift issues early.
//  - unroll 4 (VGPR free at 1 wave/SIMD).
//  - N_ITERS = 300 mandatory (R8: truncation fails). Arithmetic bit-identical
//    to R9 (same expressions, reordered scheduling only).
// ---------------------------------------------------------------------------

#define TT 48
#define N_ITERS 300

typedef float v2 __attribute__((ext_vector_type(2)));

__device__ __forceinline__ v2 vfma(v2 a, v2 b, v2 c) {
    return __builtin_elementwise_fma(a, b, c);
}
__device__ __forceinline__ v2 vmax0(v2 a) {
    return __builtin_elementwise_max(a, (v2)(0.f));
}

// lane l <- v[l-1] (whole wave), lane 0 <- v[48]
__device__ __forceinline__ float shift_up(float v, bool is0) {
    int iv  = __float_as_int(v);
    int s48 = __builtin_amdgcn_readlane(iv, 48);
    int sh  = __builtin_amdgcn_update_dpp(iv, iv, 0x138, 0xF, 0xF, false); // wave_shr:1
    sh = is0 ? s48 : sh;
    return __int_as_float(sh);
}

// lane l <- v[l+1] (whole wave), lane 48 <- v[0]
__device__ __forceinline__ float shift_dn(float v, bool is48) {
    int iv = __float_as_int(v);
    int s0 = __builtin_amdgcn_readlane(iv, 0);
    int sh = __builtin_amdgcn_update_dpp(iv, iv, 0x130, 0xF, 0xF, false); // wave_shl:1
    sh = is48 ? s0 : sh;
    return __int_as_float(sh);
}

__global__ __launch_bounds__(64) void pdhg_kernel(
    const float* __restrict__ price,
    const float* __restrict__ loadv,
    const float* __restrict__ pvv,
    const float* __restrict__ s0,
    float* __restrict__ out,
    int B,
    float tau)
{
    const int b = blockIdx.x;
    const int t = threadIdx.x;
    const bool lt  = (t < TT);
    const bool i48 = (t == TT);
    const bool i0  = (t == 0);

    const float A  = 0.999f;
    const float Bi = 0.95f;    // B00
    const float Bo = -1.05f;   // B01
    const float ts = tau * tau;     // tau*sigma (sigma == tau)

    float pr_ = 0.f, ld = 0.f, pv_ = 0.f;
    if (lt) {
        pr_ = price[(size_t)b*TT + t];
        ld  = loadv[(size_t)b*TT + t];
        pv_ = pvv  [(size_t)b*TT + t];
    }
    const float qe   = i48 ? s0[b] : 0.f;   // b_eq: zeros(T) then s0
    const float tsqe = ts * qe;

    // hoisted per-lane constants (zeroed on lanes >= 48 where needed so the
    // kts / u paths need no cndmask; G12 stays pinned at 0 there)
    const v2 tsv   = (v2)(ts);
    const v2 ntsv  = (v2)(-ts);
    const v2 npts  = lt ? (v2){ -ts, ts } : (v2){ 0.f, 0.f };
    const v2 BiBov = { -Bi, -Bo };
    const float Avec  = lt ? A       : 0.f;
    const float tsAl  = lt ? ts * A  : 0.f;
    const float tsBil = lt ? ts * Bi : 0.f;
    const float tsBol = lt ? ts * Bo : 0.f;
    const v2 tpv   = { tau * pr_, -tau * pr_ };    // tau*c for (in,out)/(pl,pr)
    const float tep = tau * 1.0e4f;                // tau*c_eps
    const v2 LDPV  = { ld, pv_ };                  // zPP' shift
    const float dlp = ld - pv_;                    // m11 constant offset
    const v2 C12    = lt ? (v2){ 0.f, ts * 13.5f } : (v2){ 0.f, 0.f };
    const v2 C35    = { ts * 5.f, ts * 5.f };
    const v2 C1112d = { ts * (10.f - dlp), ts * (10.f + dlp) };

    // primal state: pairs (in,out), (pl,pr), (s,eps)
    v2 xIO = (v2)(0.f), xPP = (v2)(0.f), xSE = (v2)(0.f);
    // dual state (scaled by tau): ye scalar (+ yprev = shifted ye); rows paired
    float ye = 0.f, yprev = 0.f;
    v2 G12 = (v2)(0.f), G35 = (v2)(0.f), G46 = (v2)(0.f),
       G79 = (v2)(0.f), G810 = (v2)(0.f), G1112 = (v2)(0.f);

    // loop-carried K^T-side diffs (tail-computed; zero at G=0)
    float dG12 = 0.f, Ssum = 0.f;
    v2 sumIO = (v2)(0.f), dv = (v2)(0.f), dPP = (v2)(0.f);

    #pragma unroll 4
    for (int it = 0; it < N_ITERS; ++it) {
        // ---- s-path first: kts depends only on loop-carried values ----
        // lanes >= 48: G12 pinned 0 (dG12=0), Avec = 0 -> kts = yprev
        const float kts = fmaf(-Avec, ye, yprev + dG12);

        // ---- K^T y head (all operands precomputed in previous tail) ----
        const v2 ktIO  = vfma((v2)(ye), BiBov, sumIO + dv);
        const v2 ktPP  = dPP + dv;
        const float wep = tep - Ssum;               // tau*(c_ep + ktep)

        // ---- x' = x - w;  z = x - 2w ----
        const v2 wIO = ktIO + tpv;
        const v2 wPP = ktPP + tpv;
        const v2 wSE = { kts, wep };
        const v2 xnIO = xIO - wIO;  const v2 zIO = vfma(wIO, (v2)(-2.f), xIO);
        const v2 xnPP = xPP - wPP;  const v2 zPP = vfma(wPP, (v2)(-2.f), xPP);
        const v2 xnSE = xSE - wSE;  const v2 zSE = vfma(wSE, (v2)(-2.f), xSE);
        const float zs = zSE.x;

        // ---- down-shift of zs as early as possible ----
        const float zsn = shift_dn(zs, i48);        // lane48 <- zs[0]

        // ---- u package: ye - ts*qe + ts*(own-lane part of K z eq-row) ----
        // (tsAl/tsBil/tsBol zeroed on lanes >= 48 -> u = ye - tsqe there)
        float u = ye - tsqe;
        u = fmaf(-tsBol, zIO.y, u);
        u = fmaf(-tsBil, zIO.x, u);
        u = fmaf(-tsAl,  zs,    u);
        const float us = shift_up(u, i0);           // lane0 <- u[48]

        // ---- dual rows: G' = max(G + ts*e - ts*h, 0) ----
        const v2 zPP2 = zPP - LDPV;                 // (zpl-ld, zpr-pv)
        const v2 sv   = zPP2 + zSE.yy;
        const v2 dvv  = zPP2 - zSE.yy;
        const v2 S2   = zIO + zPP2;
        const v2 m11v = S2 - S2.yx;                 // {m11-dlp, -(m11-dlp)}

        G12   = vmax0(vfma(zSE.xx, npts, G12) - C12);
        G35   = vmax0(vfma(zIO,  tsv,  G35)  - C35);
        G46   = vmax0(vfma(zIO,  ntsv, G46));
        G79   = vmax0(vfma(sv,   ntsv, G79));           // C79 folded into zPP2
        G810  = vmax0(vfma(dvv,  tsv,  G810));          // C810 folded into zPP2
        G1112 = vmax0(vfma(m11v, tsv,  G1112) - C1112d);

        // ---- tail: K^T-side diffs for the NEXT head (overlap with ye ops) ----
        dG12  = G12.y - G12.x;
        sumIO = G35 - G46;
        dv    = G1112 - G1112.yx;
        dPP   = G810 - G79;
        const v2 S = G79 + G810;
        Ssum  = S.x + S.y;

        // ---- equality dual + pre-shifted ye for next iteration ----
        ye    = fmaf(ts, zsn, u);                   // ye_{i+1}[l]
        yprev = fmaf(ts, zs,  us);                  // ye_{i+1}[l-1] (wrap at 0)

        xSE = xnSE; xIO = xnIO; xPP = xnPP;
    }

    if (lt) {
        const size_t BT   = (size_t)B * TT;
        const size_t base = (size_t)b * TT + t;
        out[0*BT + base] = xIO.x;  // Ps_in
        out[1*BT + base] = xIO.y;  // Ps_out
        out[2*BT + base] = xPP.x;  // Pl
        out[3*BT + base] = xPP.y;  // Pr
        out[4*BT + base] = xSE.y;  // eps
    }
}

// ---------------------------------------------------------------------------
// Host: ||K||_2 via matrix-free Lanczos (m=56, no reorth) on M = K^T K
// (289-dim closed form), lambda_max(T_m) via Sturm bisection. Deterministic.
// ---------------------------------------------------------------------------
static float compute_tau_host()
{
    const double A = 0.999, Bi = 0.95, Bo = -1.05;
    const int n = 289;            // 49 + 5*48
    const int OS = 0, OI = 49, OO = 97, OPL = 145, OPR = 193, OE = 241;

    double q[289], qp[289], w[289];

    auto applyM = [&](const double* v, double* u) {
        double we[TT + 1];
        for (int t = 0; t < TT; ++t)
            we[t] = v[OS + t + 1] - A * v[OS + t] - Bi * v[OI + t] - Bo * v[OO + t];
        we[TT] = v[OS + 0];
        for (int j = 0; j <= TT; ++j) {
            double r = (j >= 1) ? we[j - 1] : we[TT];
            if (j <= TT - 1) r += -A * we[j] + 2.0 * v[OS + j];
            u[OS + j] = r;
        }
        for (int t = 0; t < TT; ++t) {
            const double w11 = v[OI + t] - v[OO + t] + v[OPL + t] - v[OPR + t];
            u[OI  + t] = -Bi * we[t] + 2.0 * v[OI  + t] + 2.0 * w11;
            u[OO  + t] = -Bo * we[t] + 2.0 * v[OO  + t] - 2.0 * w11;
            u[OPL + t] =  2.0 * v[OPL + t] + 2.0 * w11;
            u[OPR + t] =  2.0 * v[OPR + t] - 2.0 * w11;
            u[OE  + t] =  4.0 * v[OE  + t];
        }
    };

    // deterministic init, normalized
    unsigned long long lcg = 0x243F6A8885A308D3ull;
    for (int i = 0; i < n; ++i) {
        lcg = lcg * 6364136223846793005ull + 1442695040888963407ull;
        q[i] = ((double)(lcg >> 11) / 9007199254740992.0) - 0.5;
    }
    {
        double s = 0; for (int i = 0; i < n; ++i) s += q[i]*q[i];
        const double inv = 1.0 / sqrt(s);
        for (int i = 0; i < n; ++i) q[i] *= inv;
    }

    const int MMAX = 56;
    double alpha[MMAX], beta[MMAX];
    for (int i = 0; i < n; ++i) qp[i] = 0.0;
    double bprev = 0.0;
    int m = MMAX;
    for (int j = 0; j < MMAX; ++j) {
        applyM(q, w);
        if (j > 0) for (int i = 0; i < n; ++i) w[i] -= bprev * qp[i];
        double a = 0; for (int i = 0; i < n; ++i) a += w[i] * q[i];
        alpha[j] = a;
        for (int i = 0; i < n; ++i) w[i] -= a * q[i];
        double s = 0; for (int i = 0; i < n; ++i) s += w[i]*w[i];
        const double bnx = sqrt(s);
        if (bnx < 1e-12) { m = j + 1; break; }
        beta[j] = bnx;
        const double inv = 1.0 / bnx;
        for (int i = 0; i < n; ++i) { qp[i] = q[i]; q[i] = w[i] * inv; }
        bprev = bnx;
    }

    double hi = 0.0;
    for (int i = 0; i < m; ++i) {
        double g = alpha[i] + (i > 0 ? fabs(beta[i-1]) : 0.0)
                            + (i < m-1 ? fabs(beta[i]) : 0.0);
        if (g > hi) hi = g;
    }
    hi += 1e-9; double lo = 0.0;
    for (int it = 0; it < 64; ++it) {
        const double mid = 0.5 * (lo + hi);
        int cnt = 0; double d = 1.0;
        for (int i = 0; i < m; ++i) {
            double tt = alpha[i] - mid - (i > 0 ? beta[i-1]*beta[i-1] / d : 0.0);
            if (tt < 0) ++cnt;
            if (fabs(tt) < 1e-30) tt = -1e-30;
            d = tt;
        }
        if (cnt >= m) hi = mid; else lo = mid;
    }
    double lam = 0.5 * (lo + hi);

    applyM(q, w);
    double rq = 0, nq = 0;
    for (int i = 0; i < n; ++i) { rq += q[i]*w[i]; nq += q[i]*q[i]; }
    rq /= nq;
    if (rq > lam) lam = rq;

    return (float)(0.95 / sqrt(lam));
}

extern "C" void kernel_launch(void* const* d_in, const int* in_sizes, int n_in,
                              void* d_out, int out_size, void* d_ws, size_t ws_size,
                              hipStream_t stream)
{
    const float* price = (const float*)d_in[0];
    const float* loadv = (const float*)d_in[1];
    const float* pvv   = (const float*)d_in[2];
    const float* s0    = (const float*)d_in[3];
    float* out = (float*)d_out;

    const int B = in_sizes[0] / TT;   // price_hat is (B, T)
    const float tau = compute_tau_host();

    pdhg_kernel<<<B, 64, 0, stream>>>(price, loadv, pvv, s0, out, B, tau);
}